// Round 13
// baseline (327.545 us; speedup 1.0000x reference)
//
#include <hip/hip_runtime.h>
#include <cstdint>
#include <cstddef>

// Problem constants: B=4, T=2048, C=1024, H=16, D=64, tokens M=8192.
#define MTOK 8192
#define CDIM 1024

typedef __bf16 bf16x8 __attribute__((ext_vector_type(8)));
typedef float  f32x4  __attribute__((ext_vector_type(4)));
typedef float  f32x16 __attribute__((ext_vector_type(16)));
typedef uint32_t u32x4 __attribute__((ext_vector_type(4)));

// 1/sqrt(64) * log2(e): QK^T softmax done in exp2 domain.
#define QSCALE 0.18033688011112042f

__device__ __forceinline__ uint16_t f2bf(float f) {
    return __builtin_bit_cast(uint16_t, (__bf16)f);  // HW RNE cvt (don't hand-write; m240)
}
__device__ __forceinline__ uint32_t cvtpk(float lo, float hi) {
    return (uint32_t)__builtin_bit_cast(uint16_t, (__bf16)lo) |
           ((uint32_t)__builtin_bit_cast(uint16_t, (__bf16)hi) << 16);
}

__device__ __forceinline__ void gload_lds16(const uint16_t* g, uint16_t* l) {
    __builtin_amdgcn_global_load_lds((const __attribute__((address_space(1))) void*)g,
                                     (__attribute__((address_space(3))) void*)l, 16, 0, 0);
}

// ---------------------------------------------------------------- prep kernels
__global__ __launch_bounds__(256) void convert_x_kernel(const float* __restrict__ x,
                                                        uint16_t* __restrict__ xb, int n) {
    int i = (blockIdx.x * 256 + threadIdx.x) * 4;
    int stride = gridDim.x * 256 * 4;
    for (; i < n; i += stride) {
        float4 v = *reinterpret_cast<const float4*>(x + i);
        uint64_t pk = (uint64_t)cvtpk(v.x, v.y) | ((uint64_t)cvtpk(v.z, v.w) << 32);
        *reinterpret_cast<uint64_t*>(xb + i) = pk;
    }
}

// W[k][n] f32  ->  Wt[n][k] bf16   (4 weights via blockIdx.z)
__global__ __launch_bounds__(256) void transpose_w_kernel(const float* __restrict__ W0,
                                                          const float* __restrict__ W1,
                                                          const float* __restrict__ W2,
                                                          const float* __restrict__ W3,
                                                          uint16_t* __restrict__ Wt) {
    __shared__ float tile[32][33];
    const float* W = blockIdx.z == 0 ? W0 : blockIdx.z == 1 ? W1 : blockIdx.z == 2 ? W2 : W3;
    uint16_t* out = Wt + (size_t)blockIdx.z * 1024 * 1024;
    int k0 = blockIdx.y * 32, n0 = blockIdx.x * 32;
    int tx = threadIdx.x, ty = threadIdx.y;  // block (32,8)
#pragma unroll
    for (int i = 0; i < 4; i++) tile[ty * 4 + i][tx] = W[(size_t)(k0 + ty * 4 + i) * 1024 + n0 + tx];
    __syncthreads();
#pragma unroll
    for (int i = 0; i < 4; i++) out[(size_t)(n0 + ty * 4 + i) * 1024 + k0 + tx] = f2bf(tile[tx][ty * 4 + i]);
}

// ---------------------------------------------------------------- GEMM mainloop
// 2-phase double-buffered. Round-10 A/B: neutral vs 2-barrier version (the
// syncthreads vmcnt-drain still serializes staging — consistent with learn_hip
// m99/m131-140 on this structure class). Kept: validated-correct.
__device__ __forceinline__ void gemm_stage(const uint16_t* __restrict__ A,
                                           const uint16_t* __restrict__ Wt,
                                           int m0, int n0, int k0,
                                           uint16_t* Als, uint16_t* Bls,
                                           int r, int cc, int wave) {
    gload_lds16(A + (size_t)(m0 + r) * 1024 + k0 + cc, Als + wave * 512);
    gload_lds16(A + (size_t)(m0 + 64 + r) * 1024 + k0 + cc, Als + 2048 + wave * 512);
    gload_lds16(Wt + (size_t)(n0 + r) * 1024 + k0 + cc, Bls + wave * 512);
    gload_lds16(Wt + (size_t)(n0 + 64 + r) * 1024 + k0 + cc, Bls + 2048 + wave * 512);
}

__device__ __forceinline__ void gemm128_mainloop(const uint16_t* __restrict__ A,
                                                 const uint16_t* __restrict__ Wt,
                                                 int m0, int n0,
                                                 uint16_t* Als, uint16_t* Bls,  // each [2][4096]
                                                 f32x4 acc[4][4]) {
    const int tid = threadIdx.x;
    const int wave = tid >> 6, lane = tid & 63;
    const int g = lane >> 4, c = lane & 15;
    const int wr = wave >> 1, wc = wave & 1;
    const int r = tid >> 2, cc = (tid & 3) * 8;
#pragma unroll
    for (int mi = 0; mi < 4; mi++)
#pragma unroll
        for (int ni = 0; ni < 4; ni++) acc[mi][ni] = f32x4{0.f, 0.f, 0.f, 0.f};

    // Prologue: stage K-tile 0 into buf 0.
    gemm_stage(A, Wt, m0, n0, 0, Als, Bls, r, cc, wave);
    __syncthreads();  // drains vmcnt: tile 0 resident

    int cur = 0;
    for (int k0 = 0; k0 < 1024; k0 += 32, cur ^= 1) {
        // Issue next tile's staging first; hides under this tile's ds_read+MFMA.
        if (k0 + 32 < 1024)
            gemm_stage(A, Wt, m0, n0, k0 + 32,
                       Als + (cur ^ 1) * 4096, Bls + (cur ^ 1) * 4096, r, cc, wave);
        const uint16_t* Ab = Als + cur * 4096;
        const uint16_t* Bb = Bls + cur * 4096;
        bf16x8 af[4], bf[4];
#pragma unroll
        for (int mi = 0; mi < 4; mi++)
            af[mi] = *reinterpret_cast<const bf16x8*>(Ab + (wr * 64 + mi * 16 + c) * 32 + g * 8);
#pragma unroll
        for (int ni = 0; ni < 4; ni++)
            bf[ni] = *reinterpret_cast<const bf16x8*>(Bb + (wc * 64 + ni * 16 + c) * 32 + g * 8);
#pragma unroll
        for (int mi = 0; mi < 4; mi++)
#pragma unroll
            for (int ni = 0; ni < 4; ni++)
                acc[mi][ni] = __builtin_amdgcn_mfma_f32_16x16x32_bf16(af[mi], bf[ni], acc[mi][ni], 0, 0, 0);
        __syncthreads();  // next tile staged (vmcnt) + this tile's reads done (lgkm)
    }
}

// ---------------------------------------------------------------- QKV projection
// z=0: Q = (x@Wq+bq)*QSCALE -> [B,H,T,D] bf16 (attn scale + log2e folded)
// z=1: K = x@Wk+bk          -> [B,H,T,D] bf16
// z=2: V = x@Wv+bv          -> [B,H,D,T] bf16 (transposed: PV/O^T A-frag reads)
__global__ __launch_bounds__(256) void qkv_gemm_kernel(const uint16_t* __restrict__ xb,
                                                       const uint16_t* __restrict__ WtAll,
                                                       const float* __restrict__ bq,
                                                       const float* __restrict__ bk,
                                                       const float* __restrict__ bv,
                                                       uint16_t* __restrict__ Qg,
                                                       uint16_t* __restrict__ Kg,
                                                       uint16_t* __restrict__ Vtg) {
    __shared__ uint16_t Als[8192], Bls[8192];  // 2x double-buffered 128x32 tiles
    const int z = blockIdx.z;
    const uint16_t* Wt = WtAll + (size_t)z * 1024 * 1024;
    const float* bias = z == 0 ? bq : z == 1 ? bk : bv;
    const int m0 = blockIdx.y * 128, n0 = blockIdx.x * 128;
    f32x4 acc[4][4];
    gemm128_mainloop(xb, Wt, m0, n0, Als, Bls, acc);

    const int tid = threadIdx.x, wave = tid >> 6, lane = tid & 63;
    const int g = lane >> 4, c = lane & 15;
    const int wr = wave >> 1, wc = wave & 1;
#pragma unroll
    for (int ni = 0; ni < 4; ni++) {
        int n = n0 + wc * 64 + ni * 16 + c;
        float bb = bias[n];
        int h = n >> 6, d = n & 63;
#pragma unroll
        for (int mi = 0; mi < 4; mi++)
#pragma unroll
            for (int j = 0; j < 4; j++) {
                int m = m0 + wr * 64 + mi * 16 + g * 4 + j;
                int b = m >> 11, t = m & 2047;
                float v = acc[mi][ni][j] + bb;
                size_t bhOff = (size_t)(b * 16 + h) * 131072;
                if (z == 0)      Qg[bhOff + (size_t)t * 64 + d] = f2bf(v * QSCALE);
                else if (z == 1) Kg[bhOff + (size_t)t * 64 + d] = f2bf(v);
                else             Vtg[bhOff + (size_t)d * 2048 + t] = f2bf(v);
            }
    }
}

// ---------------------------------------------------------------- flash attention
// Round-11 change (pending measurement): 64 q-rows per wave (two 32-row columns
// A/B sharing every K/V fragment read) — halves the per-CU ds_read_b128 count,
// which the round-10 model shows is attn's binding pipe (~54 us of 108).
// 256 blocks (1/CU), 8 waves. Staging/swizzle/softmax/pack identical to the
// validated kernel; per-column state duplicated with static indexing.
__global__ __launch_bounds__(512, 2) void attn_kernel(const uint16_t* __restrict__ Qg,
                                                      const uint16_t* __restrict__ Kg,
                                                      const uint16_t* __restrict__ Vtg,
                                                      uint16_t* __restrict__ Oatt) {
    const int blk = blockIdx.x;                 // 256 blocks
    const int xcd = blk & 7, j = blk >> 3;      // round-robin XCDs
    const int bh = xcd * 8 + (j >> 2);          // 8 bh per XCD, 4 q-blocks per bh
    const int q0 = (j & 3) * 512;

    const int tid = threadIdx.x, wave = tid >> 6, lane = tid & 63;
    const int lo = lane & 31, hi = lane >> 5, lo7 = lo & 7;
    const int qw = q0 + wave * 64;              // this wave: q rows [qw, qw+64)
    const uint16_t* Qb = Qg + (size_t)bh * 131072;
    const uint16_t* Kb = Kg + (size_t)bh * 131072;
    const uint16_t* Vb = Vtg + (size_t)bh * 131072;

    __shared__ __align__(16) uint16_t Kls[2][4096];  // [buf][64 rows x 64 elem], 8KB each
    __shared__ __align__(16) uint16_t Vls[2][4096];

    // Staging geometry (unchanged): wave w covers tile rows [w*8, w*8+8); lane l ->
    // LDS slot (r=w*8+l/8, chunk c'=l%8) holding logical chunk c'^(r&7); global
    // source pre-swizzled: sc = (l&7)^((l/8)&7).
    const int sr = lane >> 3;
    const int sc = (lane & 7) ^ (sr & 7);
    const int w8 = wave * 8;

    // Q B-frags for the two 32-row columns: col A rows qw+lo, col B rows qw+32+lo.
    bf16x8 qfA[4], qfB[4];
#pragma unroll
    for (int dc = 0; dc < 4; dc++) {
        qfA[dc] = *reinterpret_cast<const bf16x8*>(Qb + (size_t)(qw + lo) * 64 + dc * 16 + hi * 8);
        qfB[dc] = *reinterpret_cast<const bf16x8*>(Qb + (size_t)(qw + 32 + lo) * 64 + dc * 16 + hi * 8);
    }

    f32x16 oA0, oA1, oB0, oB1;  // O^T accum per column x d-tile
#pragma unroll
    for (int r = 0; r < 16; r++) { oA0[r] = 0.f; oA1[r] = 0.f; oB0[r] = 0.f; oB1[r] = 0.f; }
    float mA = -__builtin_inff(), lA = 0.f;
    float mB = -__builtin_inff(), lB = 0.f;

    // Prologue: stage kv-tile 0 into buf 0.
    gload_lds16(Kb + (size_t)(w8 + sr) * 64 + sc * 8, &Kls[0][wave * 512]);
    gload_lds16(Vb + (size_t)(w8 + sr) * 2048 + sc * 8, &Vls[0][wave * 512]);
    __syncthreads();  // drains vmcnt: tile 0 resident

    for (int t = 0; t < 32; ++t) {
        const int cur = t & 1;
        const uint16_t* Kc = Kls[cur];
        const uint16_t* Vc = Vls[cur];
        if (t < 31) {
            const int kvn = (t + 1) * 64;
            gload_lds16(Kb + (size_t)(kvn + w8 + sr) * 64 + sc * 8, &Kls[cur ^ 1][wave * 512]);
            gload_lds16(Vb + (size_t)(w8 + sr) * 2048 + kvn + sc * 8, &Vls[cur ^ 1][wave * 512]);
        }

        // --- S^T = mfma(K, Q) for both columns; each kf read feeds 2 MFMAs.
        f32x16 pA0, pA1, pB0, pB1;
#pragma unroll
        for (int r = 0; r < 16; r++) { pA0[r] = 0.f; pA1[r] = 0.f; pB0[r] = 0.f; pB1[r] = 0.f; }
        {
            const uint16_t* base = Kc + lo * 64;
            bf16x8 ka = *reinterpret_cast<const bf16x8*>(base + (((0 + hi) ^ lo7) * 8));
            bf16x8 kb2 = *reinterpret_cast<const bf16x8*>(base + (((2 + hi) ^ lo7) * 8));
            bf16x8 kc2 = *reinterpret_cast<const bf16x8*>(base + (((4 + hi) ^ lo7) * 8));
            bf16x8 kd = *reinterpret_cast<const bf16x8*>(base + (((6 + hi) ^ lo7) * 8));
            __builtin_amdgcn_s_setprio(1);
            pA0 = __builtin_amdgcn_mfma_f32_32x32x16_bf16(ka, qfA[0], pA0, 0, 0, 0);
            pB0 = __builtin_amdgcn_mfma_f32_32x32x16_bf16(ka, qfB[0], pB0, 0, 0, 0);
            pA0 = __builtin_amdgcn_mfma_f32_32x32x16_bf16(kb2, qfA[1], pA0, 0, 0, 0);
            pB0 = __builtin_amdgcn_mfma_f32_32x32x16_bf16(kb2, qfB[1], pB0, 0, 0, 0);
            pA0 = __builtin_amdgcn_mfma_f32_32x32x16_bf16(kc2, qfA[2], pA0, 0, 0, 0);
            pB0 = __builtin_amdgcn_mfma_f32_32x32x16_bf16(kc2, qfB[2], pB0, 0, 0, 0);
            pA0 = __builtin_amdgcn_mfma_f32_32x32x16_bf16(kd, qfA[3], pA0, 0, 0, 0);
            pB0 = __builtin_amdgcn_mfma_f32_32x32x16_bf16(kd, qfB[3], pB0, 0, 0, 0);
            __builtin_amdgcn_s_setprio(0);
        }
        {
            const uint16_t* base = Kc + (32 + lo) * 64;
            bf16x8 ka = *reinterpret_cast<const bf16x8*>(base + (((0 + hi) ^ lo7) * 8));
            bf16x8 kb2 = *reinterpret_cast<const bf16x8*>(base + (((2 + hi) ^ lo7) * 8));
            bf16x8 kc2 = *reinterpret_cast<const bf16x8*>(base + (((4 + hi) ^ lo7) * 8));
            bf16x8 kd = *reinterpret_cast<const bf16x8*>(base + (((6 + hi) ^ lo7) * 8));
            __builtin_amdgcn_s_setprio(1);
            pA1 = __builtin_amdgcn_mfma_f32_32x32x16_bf16(ka, qfA[0], pA1, 0, 0, 0);
            pB1 = __builtin_amdgcn_mfma_f32_32x32x16_bf16(ka, qfB[0], pB1, 0, 0, 0);
            pA1 = __builtin_amdgcn_mfma_f32_32x32x16_bf16(kb2, qfA[1], pA1, 0, 0, 0);
            pB1 = __builtin_amdgcn_mfma_f32_32x32x16_bf16(kb2, qfB[1], pB1, 0, 0, 0);
            pA1 = __builtin_amdgcn_mfma_f32_32x32x16_bf16(kc2, qfA[2], pA1, 0, 0, 0);
            pB1 = __builtin_amdgcn_mfma_f32_32x32x16_bf16(kc2, qfB[2], pB1, 0, 0, 0);
            pA1 = __builtin_amdgcn_mfma_f32_32x32x16_bf16(kd, qfA[3], pA1, 0, 0, 0);
            pB1 = __builtin_amdgcn_mfma_f32_32x32x16_bf16(kd, qfB[3], pB1, 0, 0, 0);
            __builtin_amdgcn_s_setprio(0);
        }

        // --- Online softmax + in-register P^T pack, column A then column B.
        bf16x8 pfA[4], pfB[4];
        {
            float mx[8];
#pragma unroll
            for (int r = 0; r < 8; r++) mx[r] = fmaxf(fmaxf(pA0[r], pA0[r + 8]), fmaxf(pA1[r], pA1[r + 8]));
            float pa = fmaxf(fmaxf(mx[0], mx[1]), fmaxf(mx[2], mx[3]));
            float pb = fmaxf(fmaxf(mx[4], mx[5]), fmaxf(mx[6], mx[7]));
            float pm = fmaxf(pa, pb);
            pm = fmaxf(pm, __shfl_xor(pm, 32));
            if (!__all(pm <= mA + 8.f)) {
                float nm = fmaxf(mA, pm);
                float al = __builtin_amdgcn_exp2f(mA - nm);
                lA *= al;
#pragma unroll
                for (int r = 0; r < 16; r++) { oA0[r] *= al; oA1[r] *= al; }
                mA = nm;
            }
            float s0 = 0.f, s1 = 0.f, s2 = 0.f, s3 = 0.f;
#pragma unroll
            for (int r = 0; r < 4; r++) {
                pA0[r]      = __builtin_amdgcn_exp2f(pA0[r] - mA);      s0 += pA0[r];
                pA0[r + 4]  = __builtin_amdgcn_exp2f(pA0[r + 4] - mA);  s1 += pA0[r + 4];
                pA0[r + 8]  = __builtin_amdgcn_exp2f(pA0[r + 8] - mA);  s2 += pA0[r + 8];
                pA0[r + 12] = __builtin_amdgcn_exp2f(pA0[r + 12] - mA); s3 += pA0[r + 12];
            }
#pragma unroll
            for (int r = 0; r < 4; r++) {
                pA1[r]      = __builtin_amdgcn_exp2f(pA1[r] - mA);      s0 += pA1[r];
                pA1[r + 4]  = __builtin_amdgcn_exp2f(pA1[r + 4] - mA);  s1 += pA1[r + 4];
                pA1[r + 8]  = __builtin_amdgcn_exp2f(pA1[r + 8] - mA);  s2 += pA1[r + 8];
                pA1[r + 12] = __builtin_amdgcn_exp2f(pA1[r + 12] - mA); s3 += pA1[r + 12];
            }
            float rs = (s0 + s1) + (s2 + s3);
            rs += __shfl_xor(rs, 32);
            lA += rs;
            uint32_t pk0[8], pk1[8];
#pragma unroll
            for (int rp = 0; rp < 8; rp++) {
                pk0[rp] = cvtpk(pA0[2 * rp], pA0[2 * rp + 1]);
                pk1[rp] = cvtpk(pA1[2 * rp], pA1[2 * rp + 1]);
            }
#pragma unroll
            for (int kc = 0; kc < 4; kc++) {
                const uint32_t* pk = (kc >> 1) ? pk1 : pk0;
                const int b0 = (kc & 1) * 4;
                auto sA2 = __builtin_amdgcn_permlane32_swap(pk[b0 + 0], pk[b0 + 2], false, false);
                auto sB2 = __builtin_amdgcn_permlane32_swap(pk[b0 + 1], pk[b0 + 3], false, false);
                pfA[kc] = __builtin_bit_cast(bf16x8, u32x4{(uint32_t)sA2[0], (uint32_t)sB2[0],
                                                           (uint32_t)sA2[1], (uint32_t)sB2[1]});
            }
        }
        {
            float mx[8];
#pragma unroll
            for (int r = 0; r < 8; r++) mx[r] = fmaxf(fmaxf(pB0[r], pB0[r + 8]), fmaxf(pB1[r], pB1[r + 8]));
            float pa = fmaxf(fmaxf(mx[0], mx[1]), fmaxf(mx[2], mx[3]));
            float pb = fmaxf(fmaxf(mx[4], mx[5]), fmaxf(mx[6], mx[7]));
            float pm = fmaxf(pa, pb);
            pm = fmaxf(pm, __shfl_xor(pm, 32));
            if (!__all(pm <= mB + 8.f)) {
                float nm = fmaxf(mB, pm);
                float al = __builtin_amdgcn_exp2f(mB - nm);
                lB *= al;
#pragma unroll
                for (int r = 0; r < 16; r++) { oB0[r] *= al; oB1[r] *= al; }
                mB = nm;
            }
            float s0 = 0.f, s1 = 0.f, s2 = 0.f, s3 = 0.f;
#pragma unroll
            for (int r = 0; r < 4; r++) {
                pB0[r]      = __builtin_amdgcn_exp2f(pB0[r] - mB);      s0 += pB0[r];
                pB0[r + 4]  = __builtin_amdgcn_exp2f(pB0[r + 4] - mB);  s1 += pB0[r + 4];
                pB0[r + 8]  = __builtin_amdgcn_exp2f(pB0[r + 8] - mB);  s2 += pB0[r + 8];
                pB0[r + 12] = __builtin_amdgcn_exp2f(pB0[r + 12] - mB); s3 += pB0[r + 12];
            }
#pragma unroll
            for (int r = 0; r < 4; r++) {
                pB1[r]      = __builtin_amdgcn_exp2f(pB1[r] - mB);      s0 += pB1[r];
                pB1[r + 4]  = __builtin_amdgcn_exp2f(pB1[r + 4] - mB);  s1 += pB1[r + 4];
                pB1[r + 8]  = __builtin_amdgcn_exp2f(pB1[r + 8] - mB);  s2 += pB1[r + 8];
                pB1[r + 12] = __builtin_amdgcn_exp2f(pB1[r + 12] - mB); s3 += pB1[r + 12];
            }
            float rs = (s0 + s1) + (s2 + s3);
            rs += __shfl_xor(rs, 32);
            lB += rs;
            uint32_t pk0[8], pk1[8];
#pragma unroll
            for (int rp = 0; rp < 8; rp++) {
                pk0[rp] = cvtpk(pB0[2 * rp], pB0[2 * rp + 1]);
                pk1[rp] = cvtpk(pB1[2 * rp], pB1[2 * rp + 1]);
            }
#pragma unroll
            for (int kc = 0; kc < 4; kc++) {
                const uint32_t* pk = (kc >> 1) ? pk1 : pk0;
                const int b0 = (kc & 1) * 4;
                auto sA2 = __builtin_amdgcn_permlane32_swap(pk[b0 + 0], pk[b0 + 2], false, false);
                auto sB2 = __builtin_amdgcn_permlane32_swap(pk[b0 + 1], pk[b0 + 3], false, false);
                pfB[kc] = __builtin_bit_cast(bf16x8, u32x4{(uint32_t)sA2[0], (uint32_t)sB2[0],
                                                           (uint32_t)sA2[1], (uint32_t)sB2[1]});
            }
        }

        // --- O^T += mfma(V^T, P^T); each vf read feeds 2 MFMAs (columns A,B).
        {
            const uint16_t* base = Vc + lo * 64;
            bf16x8 va = *reinterpret_cast<const bf16x8*>(base + (((0 + hi) ^ lo7) * 8));
            bf16x8 vb2 = *reinterpret_cast<const bf16x8*>(base + (((2 + hi) ^ lo7) * 8));
            bf16x8 vc2 = *reinterpret_cast<const bf16x8*>(base + (((4 + hi) ^ lo7) * 8));
            bf16x8 vd = *reinterpret_cast<const bf16x8*>(base + (((6 + hi) ^ lo7) * 8));
            __builtin_amdgcn_s_setprio(1);
            oA0 = __builtin_amdgcn_mfma_f32_32x32x16_bf16(va, pfA[0], oA0, 0, 0, 0);
            oB0 = __builtin_amdgcn_mfma_f32_32x32x16_bf16(va, pfB[0], oB0, 0, 0, 0);
            oA0 = __builtin_amdgcn_mfma_f32_32x32x16_bf16(vb2, pfA[1], oA0, 0, 0, 0);
            oB0 = __builtin_amdgcn_mfma_f32_32x32x16_bf16(vb2, pfB[1], oB0, 0, 0, 0);
            oA0 = __builtin_amdgcn_mfma_f32_32x32x16_bf16(vc2, pfA[2], oA0, 0, 0, 0);
            oB0 = __builtin_amdgcn_mfma_f32_32x32x16_bf16(vc2, pfB[2], oB0, 0, 0, 0);
            oA0 = __builtin_amdgcn_mfma_f32_32x32x16_bf16(vd, pfA[3], oA0, 0, 0, 0);
            oB0 = __builtin_amdgcn_mfma_f32_32x32x16_bf16(vd, pfB[3], oB0, 0, 0, 0);
            __builtin_amdgcn_s_setprio(0);
        }
        {
            const uint16_t* base = Vc + (32 + lo) * 64;
            bf16x8 va = *reinterpret_cast<const bf16x8*>(base + (((0 + hi) ^ lo7) * 8));
            bf16x8 vb2 = *reinterpret_cast<const bf16x8*>(base + (((2 + hi) ^ lo7) * 8));
            bf16x8 vc2 = *reinterpret_cast<const bf16x8*>(base + (((4 + hi) ^ lo7) * 8));
            bf16x8 vd = *reinterpret_cast<const bf16x8*>(base + (((6 + hi) ^ lo7) * 8));
            __builtin_amdgcn_s_setprio(1);
            oA1 = __builtin_amdgcn_mfma_f32_32x32x16_bf16(va, pfA[0], oA1, 0, 0, 0);
            oB1 = __builtin_amdgcn_mfma_f32_32x32x16_bf16(va, pfB[0], oB1, 0, 0, 0);
            oA1 = __builtin_amdgcn_mfma_f32_32x32x16_bf16(vb2, pfA[1], oA1, 0, 0, 0);
            oB1 = __builtin_amdgcn_mfma_f32_32x32x16_bf16(vb2, pfB[1], oB1, 0, 0, 0);
            oA1 = __builtin_amdgcn_mfma_f32_32x32x16_bf16(vc2, pfA[2], oA1, 0, 0, 0);
            oB1 = __builtin_amdgcn_mfma_f32_32x32x16_bf16(vc2, pfB[2], oB1, 0, 0, 0);
            oA1 = __builtin_amdgcn_mfma_f32_32x32x16_bf16(vd, pfA[3], oA1, 0, 0, 0);
            oB1 = __builtin_amdgcn_mfma_f32_32x32x16_bf16(vd, pfB[3], oB1, 0, 0, 0);
            __builtin_amdgcn_s_setprio(0);
        }

        __syncthreads();  // next tile staged (vmcnt) + this step's reads done (lgkm)
    }

    // Epilogue: normalize per column, write O^T -> token-major Oatt[M][C] bf16.
    const int b = bh >> 4, h = bh & 15;
    {
        float inv = 1.0f / lA;
        uint16_t* orow = Oatt + (size_t)(b * 2048 + qw + lo) * 1024 + h * 64;
#pragma unroll
        for (int dt = 0; dt < 2; dt++) {
#pragma unroll
            for (int rg = 0; rg < 4; rg++) {
                int dbase = dt * 32 + rg * 8 + hi * 4;
                float v0 = (dt ? oA1[rg * 4 + 0] : oA0[rg * 4 + 0]) * inv;
                float v1 = (dt ? oA1[rg * 4 + 1] : oA0[rg * 4 + 1]) * inv;
                float v2 = (dt ? oA1[rg * 4 + 2] : oA0[rg * 4 + 2]) * inv;
                float v3 = (dt ? oA1[rg * 4 + 3] : oA0[rg * 4 + 3]) * inv;
                uint2 val;
                val.x = cvtpk(v0, v1);
                val.y = cvtpk(v2, v3);
                *reinterpret_cast<uint2*>(orow + dbase) = val;
            }
        }
    }
    {
        float inv = 1.0f / lB;
        uint16_t* orow = Oatt + (size_t)(b * 2048 + qw + 32 + lo) * 1024 + h * 64;
#pragma unroll
        for (int dt = 0; dt < 2; dt++) {
#pragma unroll
            for (int rg = 0; rg < 4; rg++) {
                int dbase = dt * 32 + rg * 8 + hi * 4;
                float v0 = (dt ? oB1[rg * 4 + 0] : oB0[rg * 4 + 0]) * inv;
                float v1 = (dt ? oB1[rg * 4 + 1] : oB0[rg * 4 + 1]) * inv;
                float v2 = (dt ? oB1[rg * 4 + 2] : oB0[rg * 4 + 2]) * inv;
                float v3 = (dt ? oB1[rg * 4 + 3] : oB0[rg * 4 + 3]) * inv;
                uint2 val;
                val.x = cvtpk(v0, v1);
                val.y = cvtpk(v2, v3);
                *reinterpret_cast<uint2*>(orow + dbase) = val;
            }
        }
    }
}

// ---------------------------------------------------------------- output projection (f32 out)
__global__ __launch_bounds__(256) void out_gemm_kernel(const uint16_t* __restrict__ Oatt,
                                                       const uint16_t* __restrict__ WtO,
                                                       const float* __restrict__ bo,
                                                       float* __restrict__ out) {
    __shared__ uint16_t Als[8192], Bls[8192];  // 2x double-buffered 128x32 tiles
    const int m0 = blockIdx.y * 128, n0 = blockIdx.x * 128;
    f32x4 acc[4][4];
    gemm128_mainloop(Oatt, WtO, m0, n0, Als, Bls, acc);

    const int tid = threadIdx.x, wave = tid >> 6, lane = tid & 63;
    const int g = lane >> 4, c = lane & 15;
    const int wr = wave >> 1, wc = wave & 1;
#pragma unroll
    for (int ni = 0; ni < 4; ni++) {
        int n = n0 + wc * 64 + ni * 16 + c;
        float bb = bo[n];
#pragma unroll
        for (int mi = 0; mi < 4; mi++)
#pragma unroll
            for (int j = 0; j < 4; j++) {
                int m = m0 + wr * 64 + mi * 16 + g * 4 + j;
                out[(size_t)m * 1024 + n] = acc[mi][ni][j] + bb;
            }
    }
}

// ---------------------------------------------------------------- launch
extern "C" void kernel_launch(void* const* d_in, const int* in_sizes, int n_in,
                              void* d_out, int out_size, void* d_ws, size_t ws_size,
                              hipStream_t stream) {
    const float* x  = (const float*)d_in[0];
    const float* Wq = (const float*)d_in[1];
    const float* bq = (const float*)d_in[2];
    const float* Wk = (const float*)d_in[3];
    const float* bk = (const float*)d_in[4];
    const float* Wv = (const float*)d_in[5];
    const float* bv = (const float*)d_in[6];
    const float* Wo = (const float*)d_in[7];
    const float* bo = (const float*)d_in[8];
    float* out = (float*)d_out;

    char* ws = (char*)d_ws;
    uint16_t* xb   = (uint16_t*)(ws);
    uint16_t* Wt   = (uint16_t*)(ws + 16777216);
    uint16_t* Qg   = (uint16_t*)(ws + 25165824);
    uint16_t* Kg   = (uint16_t*)(ws + 41943040);
    uint16_t* Vtg  = (uint16_t*)(ws + 58720256);
    uint16_t* Oatt = (uint16_t*)(ws);  // reuse xb region (xb dead after qkv_gemm)

    convert_x_kernel<<<4096, 256, 0, stream>>>(x, xb, MTOK * CDIM);
    transpose_w_kernel<<<dim3(32, 32, 4), dim3(32, 8), 0, stream>>>(Wq, Wk, Wv, Wo, Wt);
    qkv_gemm_kernel<<<dim3(8, 64, 3), 256, 0, stream>>>(xb, Wt, bq, bk, bv, Qg, Kg, Vtg);
    attn_kernel<<<256, 512, 0, stream>>>(Qg, Kg, Vtg, Oatt);
    out_gemm_kernel<<<dim3(8, 64), 256, 0, stream>>>(Oatt, Wt + (size_t)3 * 1048576, bo, out);
}